// Round 1
// baseline (6780.936 us; speedup 1.0000x reference)
//
#include <hip/hip_runtime.h>

// OT_Loss: Sinkhorn-Knopp, B=4 images, N=1024 points, M=128x128 density grid.
// K = exp(-d^2/10) underflows past d~32px -> each point touches <= 7x7 cells
// (dropped entries bounded: u*K <= 1e-21 << eps=1e-16 floor). One image per
// 1024-thread workgroup; v/KTu in LDS (64KB), K in VGPRs (49/thread).

#define GRID_N 128
#define NCELL (GRID_N * GRID_N)
#define NPTS 1024
#define NIMG 4
#define WIN 7
#define WHALF 3
#define NITER 100

__global__ __launch_bounds__(1024) void ot_sinkhorn_kernel(
    const float* __restrict__ dens,   // [NIMG, NCELL] normed density
    const float* __restrict__ pts,    // [NIMG, NPTS, 2]
    float* __restrict__ ws)           // [NIMG] per-image loss
{
    const int img = blockIdx.x;
    const int t   = threadIdx.x;

    __shared__ float sv[NCELL];   // holds KTu, then v (in place)
    __shared__ float red[16];

    // ---- per-thread point & K window setup ----
    const float px = pts[(size_t)img * NPTS * 2 + t * 2 + 0];
    const float py = pts[(size_t)img * NPTS * 2 + t * 2 + 1];

    int kc = (int)(px * 0.125f); kc = kc < 0 ? 0 : (kc > GRID_N - 1 ? GRID_N - 1 : kc);
    int kr = (int)(py * 0.125f); kr = kr < 0 ? 0 : (kr > GRID_N - 1 ? GRID_N - 1 : kr);
    int c_lo = kc - WHALF; c_lo = c_lo < 0 ? 0 : (c_lo > GRID_N - WIN ? GRID_N - WIN : c_lo);
    int r_lo = kr - WHALF; r_lo = r_lo < 0 ? 0 : (r_lo > GRID_N - WIN ? GRID_N - WIN : r_lo);

    float dx2[WIN], dy2[WIN];
#pragma unroll
    for (int j = 0; j < WIN; ++j) {
        float dx = px - (float)(8 * (c_lo + j) + 4);
        float dy = py - (float)(8 * (r_lo + j) + 4);
        dx2[j] = dx * dx;
        dy2[j] = dy * dy;
    }

    // K = exp(-d2/10) = exp2(d2 * (-log2(e)/10))
    const float C2 = -0.14426950408889634f;
    float K[WIN * WIN];
#pragma unroll
    for (int wy = 0; wy < WIN; ++wy)
#pragma unroll
        for (int wx = 0; wx < WIN; ++wx)
            K[wy * WIN + wx] = exp2f(C2 * (dx2[wx] + dy2[wy]));

    const int lbase = r_lo * GRID_N + c_lo;

    // ---- per-thread density slice (16 cells each) ----
    float breg[16];
    const float4* d4 = reinterpret_cast<const float4*>(dens + (size_t)img * NCELL + t * 16);
#pragma unroll
    for (int j = 0; j < 4; ++j) {
        float4 v = d4[j];
        breg[j * 4 + 0] = v.x; breg[j * 4 + 1] = v.y;
        breg[j * 4 + 2] = v.z; breg[j * 4 + 3] = v.w;
    }

    const float A   = 1.0f / (float)NPTS;
    const float EPS = 1e-16f;
    float u = A;

    float4* sv4 = reinterpret_cast<float4*>(sv);

    for (int it = 0; it < NITER; ++it) {
        __syncthreads();               // prev gather done before we zero
        // zero KTu
#pragma unroll
        for (int j = 0; j < 4; ++j)
            sv4[t * 4 + j] = make_float4(0.f, 0.f, 0.f, 0.f);
        __syncthreads();
        // KTu scatter: sv[j] += u * K_ij
#pragma unroll
        for (int wy = 0; wy < WIN; ++wy)
#pragma unroll
            for (int wx = 0; wx < WIN; ++wx)
                atomicAdd(&sv[lbase + wy * GRID_N + wx], u * K[wy * WIN + wx]);
        __syncthreads();
        // v = b / (KTu + eps), in place
#pragma unroll
        for (int j = 0; j < 16; ++j) {
            int c = t * 16 + j;
            sv[c] = breg[j] / (sv[c] + EPS);
        }
        __syncthreads();
        // Kv gather
        float kv = 0.f;
#pragma unroll
        for (int wy = 0; wy < WIN; ++wy)
#pragma unroll
            for (int wx = 0; wx < WIN; ++wx)
                kv = fmaf(K[wy * WIN + wx], sv[lbase + wy * GRID_N + wx], kv);
        u = A / (kv + EPS);
    }

    // ---- loss: sum_j dis_ij * u_i * K_ij * v_j ----
    float li = 0.f;
#pragma unroll
    for (int wy = 0; wy < WIN; ++wy)
#pragma unroll
        for (int wx = 0; wx < WIN; ++wx) {
            float dis = dx2[wx] + dy2[wy];
            li = fmaf(K[wy * WIN + wx] * dis, sv[lbase + wy * GRID_N + wx], li);
        }
    li *= u;

    // block reduction (16 waves of 64)
#pragma unroll
    for (int o = 32; o > 0; o >>= 1)
        li += __shfl_down(li, o);
    const int wave = t >> 6;
    const int lane = t & 63;
    if (lane == 0) red[wave] = li;
    __syncthreads();
    if (t == 0) {
        float s = 0.f;
#pragma unroll
        for (int w = 0; w < 16; ++w) s += red[w];
        ws[img] = s;
    }
}

__global__ void ot_finalize_kernel(const float* __restrict__ ws, float* __restrict__ out)
{
    float s = ws[0] + ws[1] + ws[2] + ws[3];
    out[0] = s;      // loss
    out[1] = s;      // wd
    out[2] = 0.f;    // ot_obj_values
}

extern "C" void kernel_launch(void* const* d_in, const int* in_sizes, int n_in,
                              void* d_out, int out_size, void* d_ws, size_t ws_size,
                              hipStream_t stream)
{
    const float* dens = (const float*)d_in[0];   // normed_density [4,1,128,128]
    // d_in[1] = unnormed_density: unused by the reference computation
    const float* pts  = (const float*)d_in[2];   // points [4,1024,2]
    float* out = (float*)d_out;
    float* ws  = (float*)d_ws;

    ot_sinkhorn_kernel<<<NIMG, 1024, 0, stream>>>(dens, pts, ws);
    ot_finalize_kernel<<<1, 1, 0, stream>>>(ws, out);
}

// Round 3
// 2516.216 us; speedup vs baseline: 2.6949x; 2.6949x over previous
//
#include <hip/hip_runtime.h>

// OT Sinkhorn loss. B=4 images, N=1024 pts, 128x128 grid, 100 iters.
// 7x7 window (R1-verified exact: dropped u*K <= 8.5e-22 << eps=1e-16 for ANY
// u <= A/eps). One WG per image (no cross-block sync). Phase A = transposed
// padded CSR gather (coalesced uint4, no atomics); phase B = 49 LDS v-gathers
// with packed-bf16 K in regs. R1: 6.78ms (LDS atomic scatter ~84cyc/op).

#define GRID_N 128
#define NCELL  16384
#define NPTS   1024
#define NIMG   4
#define WIN    7
#define WHALF  3
#define NITER  100
#define EPP    49
#define EPI    (NPTS*EPP)        // 50176
#define LMAX   128               // max entries per 16-cell group (obs ~85 max)

#define C2   (-0.14426950408889634f)   // -log2(e)/10
#define EPSF 1e-16f

// ws layout (bytes)
#define WS_LOSS_B   0            // float[4]
#define WS_COUNTS_B 64           // u32[4][16384]
#define WS_OFFS_B   262208       // u32[4][16400] (16385 used)
#define OFF_STRIDE  16400
#define WS_ENTC_B   524608       // u32[4][50176] cell-major {K22|pid10}
#define WS_ENTT_B   1327424      // u32[4][LMAX/4][1024][4] transposed padded
#define WS_CNTT_B   3424576      // u32[4][1024] padded counts
#define WS_TOTAL    3440960

__device__ __forceinline__ void window_of(float px, float py, int& r_lo, int& c_lo)
{
    int kc = (int)(px * 0.125f); kc = kc < 0 ? 0 : (kc > GRID_N-1 ? GRID_N-1 : kc);
    int kr = (int)(py * 0.125f); kr = kr < 0 ? 0 : (kr > GRID_N-1 ? GRID_N-1 : kr);
    c_lo = kc - WHALF; c_lo = c_lo < 0 ? 0 : (c_lo > GRID_N-WIN ? GRID_N-WIN : c_lo);
    r_lo = kr - WHALF; r_lo = r_lo < 0 ? 0 : (r_lo > GRID_N-WIN ? GRID_N-WIN : r_lo);
}

// ---- setup 1: count points covering each cell ----
__global__ __launch_bounds__(1024) void ot_count_kernel(
    const float* __restrict__ pts, unsigned* __restrict__ ws_u32)
{
    const int img = blockIdx.x, p = threadIdx.x;
    unsigned* counts = ws_u32 + WS_COUNTS_B/4 + img*NCELL;
    float px = pts[(img*NPTS + p)*2 + 0];
    float py = pts[(img*NPTS + p)*2 + 1];
    int r_lo, c_lo; window_of(px, py, r_lo, c_lo);
#pragma unroll
    for (int wy = 0; wy < WIN; ++wy)
#pragma unroll
        for (int wx = 0; wx < WIN; ++wx)
            atomicAdd(&counts[(r_lo+wy)*GRID_N + c_lo + wx], 1u);
}

// ---- setup 2: exclusive prefix-sum of counts -> offs ----
__global__ __launch_bounds__(1024) void ot_scan_kernel(unsigned* __restrict__ ws_u32)
{
    const int img = blockIdx.x, t = threadIdx.x;
    const unsigned* counts = ws_u32 + WS_COUNTS_B/4 + img*NCELL;
    unsigned* offs = ws_u32 + WS_OFFS_B/4 + img*OFF_STRIDE;

    unsigned c[16];
    const uint4* c4 = (const uint4*)(counts + t*16);
#pragma unroll
    for (int j = 0; j < 4; ++j) {
        uint4 v = c4[j];
        c[j*4+0]=v.x; c[j*4+1]=v.y; c[j*4+2]=v.z; c[j*4+3]=v.w;
    }
    unsigned s = 0;
#pragma unroll
    for (int k = 0; k < 16; ++k) s += c[k];

    __shared__ unsigned sc[1024];
    sc[t] = s; __syncthreads();
    for (int d = 1; d < 1024; d <<= 1) {
        unsigned x = (t >= d) ? sc[t-d] : 0u;
        __syncthreads();
        sc[t] += x;
        __syncthreads();
    }
    unsigned run = sc[t] - s;
#pragma unroll
    for (int k = 0; k < 16; ++k) { offs[t*16+k] = run; run += c[k]; }
    if (t == 1023) offs[NCELL] = run;   // = 50176
}

// ---- setup 3: fill cell-major entries {K22 | pid10}; drains counts ----
__global__ __launch_bounds__(1024) void ot_fill_kernel(
    const float* __restrict__ pts, unsigned* __restrict__ ws_u32)
{
    const int img = blockIdx.x, p = threadIdx.x;
    unsigned* counts = ws_u32 + WS_COUNTS_B/4 + img*NCELL;
    const unsigned* offs = ws_u32 + WS_OFFS_B/4 + img*OFF_STRIDE;
    unsigned* entC = ws_u32 + WS_ENTC_B/4 + img*EPI;

    float px = pts[(img*NPTS + p)*2 + 0];
    float py = pts[(img*NPTS + p)*2 + 1];
    int r_lo, c_lo; window_of(px, py, r_lo, c_lo);
#pragma unroll
    for (int wy = 0; wy < WIN; ++wy) {
        float dy = py - (float)(8*(r_lo+wy) + 4);
#pragma unroll
        for (int wx = 0; wx < WIN; ++wx) {
            float dx = px - (float)(8*(c_lo+wx) + 4);
            float K = exp2f(C2 * (dx*dx + dy*dy));
            unsigned Kb = __float_as_uint(K);
            unsigned e = ((Kb + 0x200u) & 0xFFFFFC00u) | (unsigned)p;
            int cell = (r_lo+wy)*GRID_N + c_lo + wx;
            unsigned old = atomicSub(&counts[cell], 1u);
            entC[offs[cell] + old - 1u] = e;
        }
    }
}

// ---- setup 4: transpose to per-thread padded layout with run-end flags ----
// entry: K[31:15] | flag[14] | sub[13:10] | pid[9:0]
__global__ __launch_bounds__(1024) void ot_transpose_kernel(unsigned* __restrict__ ws_u32)
{
    const int img = blockIdx.x, g = threadIdx.x;
    const unsigned* offs = ws_u32 + WS_OFFS_B/4 + img*OFF_STRIDE;
    const unsigned* entC = ws_u32 + WS_ENTC_B/4 + img*EPI;
    unsigned* entT = ws_u32 + WS_ENTT_B/4 + img*(LMAX*NPTS);
    unsigned* cntT = ws_u32 + WS_CNTT_B/4 + img*NPTS;

    unsigned k = 0;
    unsigned o0 = offs[g*16];
    for (int c = 0; c < 16; ++c) {
        unsigned o1 = offs[g*16 + c + 1];
        for (unsigned o = o0; o < o1; ++o) {
            unsigned e = entC[o];
            unsigned K17 = ((e & 0xFFFFFC00u) + 0x4000u) & 0xFFFF8000u;
            unsigned fl  = (o == o1 - 1u) ? 0x4000u : 0u;
            unsigned pk  = K17 | fl | ((unsigned)c << 10) | (e & 0x3FFu);
            if (k < LMAX) entT[(k >> 2)*(NPTS*4) + g*4 + (k & 3u)] = pk;
            ++k;
        }
        o0 = o1;
    }
    unsigned kc = k;
    while (kc & 3u) { if (kc < LMAX) entT[(kc >> 2)*(NPTS*4) + g*4 + (kc & 3u)] = 0u; ++kc; }
    cntT[g] = (kc <= LMAX) ? kc : (unsigned)LMAX;
}

// ---- main: 4 blocks (1/image), 100 iters, all state in LDS ----
__global__ __launch_bounds__(1024) void ot_main_kernel(
    const float* __restrict__ dens, const float* __restrict__ pts,
    unsigned* __restrict__ ws_u32)
{
    const int img = blockIdx.x, t = threadIdx.x;
    float* ws_f = (float*)ws_u32;
    const uint4* ET = (const uint4*)(ws_u32 + WS_ENTT_B/4 + img*(LMAX*NPTS));
    const unsigned cnt4 = ws_u32[WS_CNTT_B/4 + img*NPTS + t] >> 2;

    __shared__ float u_lds[NPTS];
    __shared__ float b_lds[NCELL];
    __shared__ float v_lds[NCELL];
    __shared__ float red[16];

    // stage density; default v = b/eps for never-touched cells (constant
    // across iters: walked cells are overwritten every iter)
#pragma unroll
    for (int kk = 0; kk < 16; ++kk) {
        int j = kk*1024 + t;
        float bj = dens[img*NCELL + j];
        b_lds[j] = bj;
        v_lds[j] = bj / EPSF;
    }
    const float A = 1.0f / (float)NPTS;
    u_lds[t] = A;

    // point-side setup: packed bf16 K (25 regs)
    const float px = pts[(img*NPTS + t)*2 + 0];
    const float py = pts[(img*NPTS + t)*2 + 1];
    int r_lo, c_lo; window_of(px, py, r_lo, c_lo);
    const int lbase = r_lo*GRID_N + c_lo;
    unsigned Kp[25];
#pragma unroll
    for (int i = 0; i < 25; ++i) Kp[i] = 0u;
#pragma unroll
    for (int q = 0; q < 49; ++q) {
        int wy = q / 7, wx = q % 7;
        float dx = px - (float)(8*(c_lo+wx) + 4);
        float dy = py - (float)(8*(r_lo+wy) + 4);
        float K = exp2f(C2 * (dx*dx + dy*dy));
        unsigned h = (__float_as_uint(K) + 0x8000u) >> 16;
        Kp[q >> 1] |= (q & 1) ? (h << 16) : h;
    }
    const int cb = t * 16;
    __syncthreads();

    float li = 0.f;
    for (int it = 0; it < NITER; ++it) {
        // ---- phase A: walk entries, emit v at run ends ----
        float s = 0.f;
        uint4 E = (cnt4 > 0) ? ET[t] : make_uint4(0,0,0,0);
        for (unsigned kk = 0; kk < cnt4; ++kk) {
            uint4 En = (kk + 1 < cnt4) ? ET[(kk+1)*NPTS + t] : make_uint4(0,0,0,0);
#define PROC(ee) { unsigned e_ = (ee); \
    float Ke = __uint_as_float(e_ & 0xFFFF8000u); \
    s = fmaf(Ke, u_lds[e_ & 0x3FFu], s); \
    if (e_ & 0x4000u) { int j = cb + (int)((e_ >> 10) & 15u); \
        v_lds[j] = b_lds[j] / (s + EPSF); s = 0.f; } }
            PROC(E.x) PROC(E.y) PROC(E.z) PROC(E.w)
#undef PROC
            E = En;
        }
        __syncthreads();

        // ---- phase B: Kv gather (+ dis-weighted for loss) ----
        float kv = 0.f, kd = 0.f;
#pragma unroll
        for (int q = 0; q < 49; ++q) {
            int wy = q / 7, wx = q % 7;
            float vj = v_lds[lbase + wy*GRID_N + wx];
            unsigned kb = (q & 1) ? (Kp[q >> 1] & 0xFFFF0000u) : (Kp[q >> 1] << 16);
            float Kq = __uint_as_float(kb);
            kv = fmaf(Kq, vj, kv);
            float dx = px - (float)(8*(c_lo+wx) + 4);
            float dy = py - (float)(8*(r_lo+wy) + 4);
            kd = fmaf(Kq * (dx*dx + dy*dy), vj, kd);
        }
        float u_new = A / (kv + EPSF);
        u_lds[t] = u_new;
        if (it == NITER-1) li = u_new * kd;
        __syncthreads();
    }

    // block reduction of loss
#pragma unroll
    for (int o = 32; o > 0; o >>= 1) li += __shfl_down(li, o);
    if ((t & 63) == 0) red[t >> 6] = li;
    __syncthreads();
    if (t == 0) {
        float s2 = 0.f;
#pragma unroll
        for (int w = 0; w < 16; ++w) s2 += red[w];
        ws_f[img] = s2;
    }
}

__global__ void ot_finalize_kernel(const float* __restrict__ ws_f, float* __restrict__ out)
{
    float s = ws_f[0] + ws_f[1] + ws_f[2] + ws_f[3];
    out[0] = s;
    out[1] = s;
    out[2] = 0.f;
}

// ---- fallback (ws too small): R1-verified single-kernel path ----
__global__ __launch_bounds__(1024) void ot_fallback_kernel(
    const float* __restrict__ dens, const float* __restrict__ pts,
    float* __restrict__ out)
{
    const int img = blockIdx.x, t = threadIdx.x;
    __shared__ float sv[NCELL];
    __shared__ float red[16];

    const float px = pts[(size_t)img*NPTS*2 + t*2 + 0];
    const float py = pts[(size_t)img*NPTS*2 + t*2 + 1];
    int r_lo, c_lo; window_of(px, py, r_lo, c_lo);

    float dx2[WIN], dy2[WIN];
#pragma unroll
    for (int j = 0; j < WIN; ++j) {
        float dx = px - (float)(8*(c_lo+j) + 4);
        float dy = py - (float)(8*(r_lo+j) + 4);
        dx2[j] = dx*dx; dy2[j] = dy*dy;
    }
    float K[WIN*WIN];
#pragma unroll
    for (int wy = 0; wy < WIN; ++wy)
#pragma unroll
        for (int wx = 0; wx < WIN; ++wx)
            K[wy*WIN+wx] = exp2f(C2 * (dx2[wx] + dy2[wy]));

    const int lbase = r_lo*GRID_N + c_lo;
    float breg[16];
    const float4* d4 = (const float4*)(dens + (size_t)img*NCELL + t*16);
#pragma unroll
    for (int j = 0; j < 4; ++j) {
        float4 v = d4[j];
        breg[j*4+0]=v.x; breg[j*4+1]=v.y; breg[j*4+2]=v.z; breg[j*4+3]=v.w;
    }
    const float A = 1.0f/(float)NPTS;
    float u = A;
    float4* sv4 = (float4*)sv;
    for (int it = 0; it < NITER; ++it) {
        __syncthreads();
#pragma unroll
        for (int j = 0; j < 4; ++j) sv4[t*4+j] = make_float4(0.f,0.f,0.f,0.f);
        __syncthreads();
#pragma unroll
        for (int wy = 0; wy < WIN; ++wy)
#pragma unroll
            for (int wx = 0; wx < WIN; ++wx)
                atomicAdd(&sv[lbase + wy*GRID_N + wx], u * K[wy*WIN+wx]);
        __syncthreads();
#pragma unroll
        for (int j = 0; j < 16; ++j) { int c = t*16+j; sv[c] = breg[j] / (sv[c] + EPSF); }
        __syncthreads();
        float kv = 0.f;
#pragma unroll
        for (int wy = 0; wy < WIN; ++wy)
#pragma unroll
            for (int wx = 0; wx < WIN; ++wx)
                kv = fmaf(K[wy*WIN+wx], sv[lbase + wy*GRID_N + wx], kv);
        u = A / (kv + EPSF);
    }
    float li = 0.f;
#pragma unroll
    for (int wy = 0; wy < WIN; ++wy)
#pragma unroll
        for (int wx = 0; wx < WIN; ++wx)
            li = fmaf(K[wy*WIN+wx] * (dx2[wx]+dy2[wy]), sv[lbase + wy*GRID_N + wx], li);
    li *= u;
#pragma unroll
    for (int o = 32; o > 0; o >>= 1) li += __shfl_down(li, o);
    if ((t & 63) == 0) red[t >> 6] = li;
    __syncthreads();
    if (t == 0) {
        float s = 0.f;
#pragma unroll
        for (int w = 0; w < 16; ++w) s += red[w];
        atomicAdd(&out[0], s);
        atomicAdd(&out[1], s);
    }
}

extern "C" void kernel_launch(void* const* d_in, const int* in_sizes, int n_in,
                              void* d_out, int out_size, void* d_ws, size_t ws_size,
                              hipStream_t stream)
{
    const float* dens = (const float*)d_in[0];   // [4,1,128,128]
    const float* pts  = (const float*)d_in[2];   // [4,1024,2]
    float* out = (float*)d_out;
    unsigned* ws_u32 = (unsigned*)d_ws;

    if (ws_size < (size_t)WS_TOTAL) {   // insurance: slow-but-correct path
        hipMemsetAsync(d_out, 0, 3*sizeof(float), stream);
        ot_fallback_kernel<<<NIMG, 1024, 0, stream>>>(dens, pts, out);
        return;
    }

    hipMemsetAsync((char*)d_ws + WS_COUNTS_B, 0, NIMG*NCELL*4, stream);
    ot_count_kernel    <<<NIMG, 1024, 0, stream>>>(pts, ws_u32);
    ot_scan_kernel     <<<NIMG, 1024, 0, stream>>>(ws_u32);
    ot_fill_kernel     <<<NIMG, 1024, 0, stream>>>(pts, ws_u32);
    ot_transpose_kernel<<<NIMG, 1024, 0, stream>>>(ws_u32);
    ot_main_kernel     <<<NIMG, 1024, 0, stream>>>(dens, pts, ws_u32);
    ot_finalize_kernel <<<1, 1, 0, stream>>>((const float*)d_ws, out);
}

// Round 4
// 1151.584 us; speedup vs baseline: 5.8884x; 2.1850x over previous
//
#include <hip/hip_runtime.h>

// OT Sinkhorn loss. B=4 images, N=1024 pts, 128x128 grid, 100 iters.
// R4: spatial band decomposition. Interaction radius <= 6 grid rows, so
// 16 bands x 8 rows/image have nearest-neighbor deps only. 64 WGs total,
// u/v via agent-scope (LLC-coherent) atomics, per-iter neighbor flag sync
// (release/acquire) -- no global barrier, pipelined slack.
// R3 was 2244us: 4/256 CUs, DS-pipe + serial walk bound.

#define GRID_N 128
#define NCELL  16384
#define NPTS   1024
#define NIMG   4
#define WIN    7
#define WHALF  3
#define NITER  100
#define NBAND  16
#define TPB    512
#define VROWS  14
#define EPI    (NPTS*49)

#define C2   (-0.14426950408889634f)   // -log2(e)/10
#define EPSF 1e-16f

// ws layout (bytes)
#define WS_LOSS_B   0         // f32[4]
#define WS_FLAGS_B  64        // u32[4][2][16][16]  (fA, fB; 64B stride/flag)
#define WS_U_B      8256      // f32[4][1024]
#define WS_V_B      24640     // f32[4][16384]
#define WS_BOFS_B   286784    // u32[4][32] (17 used)
#define WS_PLIST_B  287296    // u32[4][1024] band-sorted pids
#define WS_COUNTS_B 303680    // u32[4][16384]
#define WS_OFFS_B   565824    // u32[4][16400]
#define OFF_STRIDE  16400
#define WS_ENTC_B   828224    // u32[4][50176] {K22|pid10} cell-major
#define WS_TOTAL    1631040
#define ZERO_BYTES  565824    // loss+flags+u+v+bofs+plist+counts

#define AGENT __HIP_MEMORY_SCOPE_AGENT

__device__ __forceinline__ void window_of(float px, float py, int& r_lo, int& c_lo)
{
    int kc = (int)(px * 0.125f); kc = kc < 0 ? 0 : (kc > GRID_N-1 ? GRID_N-1 : kc);
    int kr = (int)(py * 0.125f); kr = kr < 0 ? 0 : (kr > GRID_N-1 ? GRID_N-1 : kr);
    c_lo = kc - WHALF; c_lo = c_lo < 0 ? 0 : (c_lo > GRID_N-WIN ? GRID_N-WIN : c_lo);
    r_lo = kr - WHALF; r_lo = r_lo < 0 ? 0 : (r_lo > GRID_N-WIN ? GRID_N-WIN : r_lo);
}

// ---- setup 1: count points covering each cell ----
__global__ __launch_bounds__(1024) void ot_count_kernel(
    const float* __restrict__ pts, unsigned* __restrict__ ws_u32)
{
    const int img = blockIdx.x, p = threadIdx.x;
    unsigned* counts = ws_u32 + WS_COUNTS_B/4 + img*NCELL;
    float px = pts[(img*NPTS + p)*2 + 0];
    float py = pts[(img*NPTS + p)*2 + 1];
    int r_lo, c_lo; window_of(px, py, r_lo, c_lo);
#pragma unroll
    for (int wy = 0; wy < WIN; ++wy)
#pragma unroll
        for (int wx = 0; wx < WIN; ++wx)
            atomicAdd(&counts[(r_lo+wy)*GRID_N + c_lo + wx], 1u);
}

// ---- setup 2: exclusive prefix-sum of counts -> offs ----
__global__ __launch_bounds__(1024) void ot_scan_kernel(unsigned* __restrict__ ws_u32)
{
    const int img = blockIdx.x, t = threadIdx.x;
    const unsigned* counts = ws_u32 + WS_COUNTS_B/4 + img*NCELL;
    unsigned* offs = ws_u32 + WS_OFFS_B/4 + img*OFF_STRIDE;

    unsigned c[16];
    const uint4* c4 = (const uint4*)(counts + t*16);
#pragma unroll
    for (int j = 0; j < 4; ++j) {
        uint4 v = c4[j];
        c[j*4+0]=v.x; c[j*4+1]=v.y; c[j*4+2]=v.z; c[j*4+3]=v.w;
    }
    unsigned s = 0;
#pragma unroll
    for (int k = 0; k < 16; ++k) s += c[k];

    __shared__ unsigned sc[1024];
    sc[t] = s; __syncthreads();
    for (int d = 1; d < 1024; d <<= 1) {
        unsigned x = (t >= d) ? sc[t-d] : 0u;
        __syncthreads();
        sc[t] += x;
        __syncthreads();
    }
    unsigned run = sc[t] - s;
#pragma unroll
    for (int k = 0; k < 16; ++k) { offs[t*16+k] = run; run += c[k]; }
    if (t == 1023) offs[NCELL] = run;   // = 50176
}

// ---- setup 3: fill cell-major entries {K22 | pid10}; drains counts ----
__global__ __launch_bounds__(1024) void ot_fill_kernel(
    const float* __restrict__ pts, unsigned* __restrict__ ws_u32)
{
    const int img = blockIdx.x, p = threadIdx.x;
    unsigned* counts = ws_u32 + WS_COUNTS_B/4 + img*NCELL;
    const unsigned* offs = ws_u32 + WS_OFFS_B/4 + img*OFF_STRIDE;
    unsigned* entC = ws_u32 + WS_ENTC_B/4 + img*EPI;

    float px = pts[(img*NPTS + p)*2 + 0];
    float py = pts[(img*NPTS + p)*2 + 1];
    int r_lo, c_lo; window_of(px, py, r_lo, c_lo);
#pragma unroll
    for (int wy = 0; wy < WIN; ++wy) {
        float dy = py - (float)(8*(r_lo+wy) + 4);
#pragma unroll
        for (int wx = 0; wx < WIN; ++wx) {
            float dx = px - (float)(8*(c_lo+wx) + 4);
            float K = exp2f(C2 * (dx*dx + dy*dy));
            unsigned Kb = __float_as_uint(K);
            unsigned e = ((Kb + 0x200u) & 0xFFFFFC00u) | (unsigned)p;
            int cell = (r_lo+wy)*GRID_N + c_lo + wx;
            unsigned old = atomicSub(&counts[cell], 1u);
            entC[offs[cell] + old - 1u] = e;
        }
    }
}

// ---- setup 4: counting-sort points by band (kr>>3); init u = 1/N ----
__global__ __launch_bounds__(1024) void ot_psort_kernel(
    const float* __restrict__ pts, unsigned* __restrict__ ws_u32)
{
    const int img = blockIdx.x, t = threadIdx.x;
    __shared__ unsigned cnt[16];
    __shared__ unsigned pos[17];
    if (t < 16) cnt[t] = 0;
    __syncthreads();
    float py = pts[(img*NPTS + t)*2 + 1];
    int kr = (int)(py * 0.125f); kr = kr < 0 ? 0 : (kr > 127 ? 127 : kr);
    int b = kr >> 3;
    atomicAdd(&cnt[b], 1u);
    __syncthreads();
    if (t == 0) {
        unsigned run = 0;
        for (int i = 0; i < 16; ++i) { pos[i] = run; run += cnt[i]; }
        pos[16] = run;
    }
    __syncthreads();
    unsigned* bofs = ws_u32 + WS_BOFS_B/4 + img*32;
    if (t < 17) bofs[t] = pos[t];
    __syncthreads();
    unsigned slot = atomicAdd(&pos[b], 1u);
    ws_u32[WS_PLIST_B/4 + img*NPTS + slot] = (unsigned)t;
    ((float*)ws_u32)[WS_U_B/4 + img*NPTS + t] = 1.0f / (float)NPTS;
}

// ---- neighbor flag wait: lanes 0/1 of wave 0 poll bnd-1 / bnd+1 ----
__device__ __forceinline__ void wait_nbrs(unsigned* fl, int bnd, unsigned target)
{
    int lane = threadIdx.x;            // called with t < 64
    int nb = (lane == 0) ? bnd - 1 : (lane == 1 ? bnd + 1 : bnd);
    nb = (nb < 0 || nb > 15) ? bnd : nb;
    unsigned* p = fl + nb*16;
    int spins = 0;
    while (__hip_atomic_load(p, __ATOMIC_ACQUIRE, AGENT) < target) {
        __builtin_amdgcn_s_sleep(2);
        if (++spins > (1<<20)) break;  // safety: never triggers if logic sound
    }
}

// ---- main: 64 WGs (4 img x 16 bands), neighbor-sync Sinkhorn ----
__global__ __launch_bounds__(TPB) void ot_main_kernel(
    const float* __restrict__ dens, const float* __restrict__ pts,
    unsigned* __restrict__ ws_u32)
{
    const int img = (int)blockIdx.x >> 4, bnd = (int)blockIdx.x & 15;
    const int t = threadIdx.x;
    float* ws_f = (float*)ws_u32;

    float*    loss  = ws_f;
    unsigned* fA    = ws_u32 + WS_FLAGS_B/4 + img*512;
    unsigned* fB    = fA + 256;
    float*    u_g   = ws_f + WS_U_B/4 + img*NPTS;
    float*    v_g   = ws_f + WS_V_B/4 + img*NCELL;
    const unsigned* bofs  = ws_u32 + WS_BOFS_B/4 + img*32;
    const unsigned* plist = ws_u32 + WS_PLIST_B/4 + img*NPTS;
    const unsigned* offs  = ws_u32 + WS_OFFS_B/4 + img*OFF_STRIDE;
    const unsigned* entC  = ws_u32 + WS_ENTC_B/4 + img*EPI;

    __shared__ float u_lds[NPTS];
    __shared__ float v_loc[VROWS*GRID_N];   // rows (8*bnd-3) .. (8*bnd+10)
    __shared__ float red[8];

    // ---- static cell side: 2 cells/thread ----
    const int myc = bnd*1024 + t*2;
    const unsigned o0 = offs[myc], o1 = offs[myc+1], o2 = offs[myc+2];
    const float bc0 = dens[img*NCELL + myc], bc1 = dens[img*NCELL + myc + 1];
    const int vb = ((t>>6) + 3)*GRID_N + ((t*2) & 127);
    const int rowbase = bnd*8 - 3;

    // ---- static point side: 4 threads/point, pass 0 precomputed ----
    const int p0 = (int)bofs[bnd], p1 = (int)bofs[bnd+1];
    const int npts = p1 - p0;
    const int sub = t & 3;
    const int idx = t >> 2;
    int mypid = -1, km = 0;
    float Kq[13], Kd2[13];
    int   cq[13];
    if (idx < npts && idx < 128) {
        mypid = (int)plist[p0 + idx];
        float px = pts[(img*NPTS + mypid)*2 + 0];
        float py = pts[(img*NPTS + mypid)*2 + 1];
        int r_lo, c_lo; window_of(px, py, r_lo, c_lo);
        int k = 0;
#pragma unroll
        for (int q = 0; q < 49; ++q) {
            if ((q & 3) == sub) {
                int wy = q / 7, wx = q % 7;
                float dx = px - (float)(8*(c_lo+wx) + 4);
                float dy = py - (float)(8*(r_lo+wy) + 4);
                float d2 = dx*dx + dy*dy;
                float K = exp2f(C2 * d2);
                Kq[k] = K; Kd2[k] = K * d2;
                cq[k] = (r_lo + wy - rowbase)*GRID_N + (c_lo + wx);
                ++k;
            }
        }
        km = k;   // 13 or 12
    }
    const int lo = (int)bofs[bnd > 0 ? bnd-1 : 0];
    const int hi = (int)bofs[bnd < 15 ? bnd+2 : 16];
    const float A = 1.0f / (float)NPTS;

    float li_acc = 0.f;

    for (int it = 0; it < NITER; ++it) {
        // wait u^{it-1} of neighbor bands published
        if (it > 0 && t < 64) wait_nbrs(fB, bnd, (unsigned)it);
        __syncthreads();

        // stage u (own + neighbor bands) into LDS
        for (int i = lo + t; i < hi; i += TPB) {
            unsigned pid = plist[i];
            u_lds[pid] = __hip_atomic_load(u_g + pid, __ATOMIC_RELAXED, AGENT);
        }
        __syncthreads();

        // ---- phase A: v = b / (K^T u + eps) for own 1024 cells ----
        float s0 = 0.f, s1 = 0.f;
        for (unsigned e = o0; e < o1; ++e) {
            unsigned E = entC[e];
            s0 = fmaf(__uint_as_float(E & 0xFFFFFC00u), u_lds[E & 0x3FFu], s0);
        }
        for (unsigned e = o1; e < o2; ++e) {
            unsigned E = entC[e];
            s1 = fmaf(__uint_as_float(E & 0xFFFFFC00u), u_lds[E & 0x3FFu], s1);
        }
        float v0 = bc0 / (s0 + EPSF), v1 = bc1 / (s1 + EPSF);
        v_loc[vb] = v0; v_loc[vb + 1] = v1;
        __hip_atomic_store(v_g + myc,     v0, __ATOMIC_RELAXED, AGENT);
        __hip_atomic_store(v_g + myc + 1, v1, __ATOMIC_RELAXED, AGENT);
        __syncthreads();
        if (t == 0)
            __hip_atomic_store(fA + bnd*16, (unsigned)(it+1), __ATOMIC_RELEASE, AGENT);

        // wait neighbor v^{it}, then stage halo rows
        if (t < 64) wait_nbrs(fA, bnd, (unsigned)(it+1));
        __syncthreads();
        for (int i = t; i < 6*GRID_N; i += TPB) {
            int rr = i >> 7, col = i & 127;
            int row  = (rr < 3) ? (rowbase + rr) : (bnd*8 + 8 + (rr - 3));
            int lidx = (rr < 3) ? (rr*GRID_N + col) : ((11 + rr - 3)*GRID_N + col);
            if (row >= 0 && row < GRID_N)
                v_loc[lidx] = __hip_atomic_load(v_g + row*GRID_N + col,
                                                __ATOMIC_RELAXED, AGENT);
        }
        __syncthreads();

        // ---- phase B: u = A / (K v + eps) for own points ----
        if (mypid >= 0) {
            float kv = 0.f, kd = 0.f;
#pragma unroll
            for (int k = 0; k < 13; ++k) {
                if (k < km) {
                    float vj = v_loc[cq[k]];
                    kv = fmaf(Kq[k],  vj, kv);
                    kd = fmaf(Kd2[k], vj, kd);
                }
            }
            kv += __shfl_xor(kv, 1); kv += __shfl_xor(kv, 2);
            float u_new = A / (kv + EPSF);
            if (sub == 0)
                __hip_atomic_store(u_g + mypid, u_new, __ATOMIC_RELAXED, AGENT);
            if (it == NITER-1) {
                kd += __shfl_xor(kd, 1); kd += __shfl_xor(kd, 2);
                if (sub == 0) li_acc += u_new * kd;
            }
        }
        // rare overflow (band with >128 points): compute K inline
        for (int base2 = 128; base2 < npts; base2 += 128) {
            int idx2 = base2 + idx;
            if (idx2 < npts) {
                int pid2 = (int)plist[p0 + idx2];
                float px = pts[(img*NPTS + pid2)*2 + 0];
                float py = pts[(img*NPTS + pid2)*2 + 1];
                int r_lo, c_lo; window_of(px, py, r_lo, c_lo);
                float kv = 0.f, kd = 0.f;
                for (int q = sub; q < 49; q += 4) {
                    int wy = q / 7, wx = q % 7;
                    float dx = px - (float)(8*(c_lo+wx) + 4);
                    float dy = py - (float)(8*(r_lo+wy) + 4);
                    float d2 = dx*dx + dy*dy;
                    float K = exp2f(C2 * d2);
                    float vj = v_loc[(r_lo + wy - rowbase)*GRID_N + c_lo + wx];
                    kv = fmaf(K, vj, kv); kd = fmaf(K*d2, vj, kd);
                }
                kv += __shfl_xor(kv, 1); kv += __shfl_xor(kv, 2);
                float u_new = A / (kv + EPSF);
                if (sub == 0)
                    __hip_atomic_store(u_g + pid2, u_new, __ATOMIC_RELAXED, AGENT);
                if (it == NITER-1) {
                    kd += __shfl_xor(kd, 1); kd += __shfl_xor(kd, 2);
                    if (sub == 0) li_acc += u_new * kd;
                }
            }
        }
        __syncthreads();
        if (t == 0)
            __hip_atomic_store(fB + bnd*16, (unsigned)(it+1), __ATOMIC_RELEASE, AGENT);
    }

    // ---- loss reduction ----
#pragma unroll
    for (int o = 32; o > 0; o >>= 1) li_acc += __shfl_down(li_acc, o);
    if ((t & 63) == 0) red[t >> 6] = li_acc;
    __syncthreads();
    if (t == 0) {
        float s = 0.f;
#pragma unroll
        for (int w = 0; w < 8; ++w) s += red[w];
        atomicAdd(&loss[img], s);
    }
}

__global__ void ot_finalize_kernel(const float* __restrict__ ws_f, float* __restrict__ out)
{
    float s = ws_f[0] + ws_f[1] + ws_f[2] + ws_f[3];
    out[0] = s;
    out[1] = s;
    out[2] = 0.f;
}

// ---- fallback (ws too small): R1-verified single-kernel path ----
__global__ __launch_bounds__(1024) void ot_fallback_kernel(
    const float* __restrict__ dens, const float* __restrict__ pts,
    float* __restrict__ out)
{
    const int img = blockIdx.x, t = threadIdx.x;
    __shared__ float sv[NCELL];
    __shared__ float redf[16];

    const float px = pts[(size_t)img*NPTS*2 + t*2 + 0];
    const float py = pts[(size_t)img*NPTS*2 + t*2 + 1];
    int r_lo, c_lo; window_of(px, py, r_lo, c_lo);

    float dx2[WIN], dy2[WIN];
#pragma unroll
    for (int j = 0; j < WIN; ++j) {
        float dx = px - (float)(8*(c_lo+j) + 4);
        float dy = py - (float)(8*(r_lo+j) + 4);
        dx2[j] = dx*dx; dy2[j] = dy*dy;
    }
    float K[WIN*WIN];
#pragma unroll
    for (int wy = 0; wy < WIN; ++wy)
#pragma unroll
        for (int wx = 0; wx < WIN; ++wx)
            K[wy*WIN+wx] = exp2f(C2 * (dx2[wx] + dy2[wy]));

    const int lbase = r_lo*GRID_N + c_lo;
    float breg[16];
    const float4* d4 = (const float4*)(dens + (size_t)img*NCELL + t*16);
#pragma unroll
    for (int j = 0; j < 4; ++j) {
        float4 v = d4[j];
        breg[j*4+0]=v.x; breg[j*4+1]=v.y; breg[j*4+2]=v.z; breg[j*4+3]=v.w;
    }
    const float A = 1.0f/(float)NPTS;
    float u = A;
    float4* sv4 = (float4*)sv;
    for (int it = 0; it < NITER; ++it) {
        __syncthreads();
#pragma unroll
        for (int j = 0; j < 4; ++j) sv4[t*4+j] = make_float4(0.f,0.f,0.f,0.f);
        __syncthreads();
#pragma unroll
        for (int wy = 0; wy < WIN; ++wy)
#pragma unroll
            for (int wx = 0; wx < WIN; ++wx)
                atomicAdd(&sv[lbase + wy*GRID_N + wx], u * K[wy*WIN+wx]);
        __syncthreads();
#pragma unroll
        for (int j = 0; j < 16; ++j) { int c = t*16+j; sv[c] = breg[j] / (sv[c] + EPSF); }
        __syncthreads();
        float kv = 0.f;
#pragma unroll
        for (int wy = 0; wy < WIN; ++wy)
#pragma unroll
            for (int wx = 0; wx < WIN; ++wx)
                kv = fmaf(K[wy*WIN+wx], sv[lbase + wy*GRID_N + wx], kv);
        u = A / (kv + EPSF);
    }
    float li = 0.f;
#pragma unroll
    for (int wy = 0; wy < WIN; ++wy)
#pragma unroll
        for (int wx = 0; wx < WIN; ++wx)
            li = fmaf(K[wy*WIN+wx] * (dx2[wx]+dy2[wy]), sv[lbase + wy*GRID_N + wx], li);
    li *= u;
#pragma unroll
    for (int o = 32; o > 0; o >>= 1) li += __shfl_down(li, o);
    if ((t & 63) == 0) redf[t >> 6] = li;
    __syncthreads();
    if (t == 0) {
        float s = 0.f;
#pragma unroll
        for (int w = 0; w < 16; ++w) s += redf[w];
        atomicAdd(&out[0], s);
        atomicAdd(&out[1], s);
    }
}

extern "C" void kernel_launch(void* const* d_in, const int* in_sizes, int n_in,
                              void* d_out, int out_size, void* d_ws, size_t ws_size,
                              hipStream_t stream)
{
    const float* dens = (const float*)d_in[0];   // [4,1,128,128]
    const float* pts  = (const float*)d_in[2];   // [4,1024,2]
    float* out = (float*)d_out;
    unsigned* ws_u32 = (unsigned*)d_ws;

    if (ws_size < (size_t)WS_TOTAL) {   // insurance: slow-but-correct path
        hipMemsetAsync(d_out, 0, 3*sizeof(float), stream);
        ot_fallback_kernel<<<NIMG, 1024, 0, stream>>>(dens, pts, out);
        return;
    }

    hipMemsetAsync(d_ws, 0, ZERO_BYTES, stream);   // loss+flags+u+v+counts
    ot_count_kernel   <<<NIMG, 1024, 0, stream>>>(pts, ws_u32);
    ot_scan_kernel    <<<NIMG, 1024, 0, stream>>>(ws_u32);
    ot_fill_kernel    <<<NIMG, 1024, 0, stream>>>(pts, ws_u32);
    ot_psort_kernel   <<<NIMG, 1024, 0, stream>>>(pts, ws_u32);
    ot_main_kernel    <<<NIMG*NBAND, TPB, 0, stream>>>(dens, pts, ws_u32);
    ot_finalize_kernel<<<1, 1, 0, stream>>>((const float*)d_ws, out);
}

// Round 5
// 1100.172 us; speedup vs baseline: 6.1635x; 1.0467x over previous
//
#include <hip/hip_runtime.h>

// OT Sinkhorn loss. B=4 images, N=1024 pts, 128x128 grid, 100 iters.
// R5: bands compute their 14-row v-halo REDUNDANTLY from u (contributors
// provably in bands b-1..b+1, incl. clamped windows) -> v never shared,
// ONE neighbor-flag sync per iter, only u (~1KB/WG/iter) crosses WGs.
// R4 was 860us: 2 syncs/iter + 89MB coherent v/u traffic (latency chain).

#define GRID_N 128
#define NCELL  16384
#define NPTS   1024
#define NIMG   4
#define WIN    7
#define WHALF  3
#define NITER  100
#define NBAND  16
#define TPB    512
#define VROWS  14
#define HCELLS (VROWS*GRID_N)   // 1792
#define EPI    (NPTS*49)

#define C2   (-0.14426950408889634f)   // -log2(e)/10
#define EPSF 1e-16f

// ws layout (bytes)
#define WS_LOSS_B   0         // f32[4]
#define WS_FLAGS_B  64        // u32[4][16][16] (64B stride per flag)
#define WS_U_B      4160      // f32[4][1024]
#define WS_BOFS_B   20544     // u32[4][32] (17 used)
#define WS_PLIST_B  21056     // u32[4][1024] band-sorted pids
#define WS_COUNTS_B 37440     // u32[4][16384]
#define WS_OFFS_B   299584    // u32[4][16400]
#define OFF_STRIDE  16400
#define WS_ENTC_B   561984    // u32[4][50176] {K22|pid10} cell-major
#define WS_TOTAL    1364800
#define ZERO_BYTES  299584    // loss+flags+u+bofs+plist+counts

#define AGENT __HIP_MEMORY_SCOPE_AGENT

__device__ __forceinline__ void window_of(float px, float py, int& r_lo, int& c_lo)
{
    int kc = (int)(px * 0.125f); kc = kc < 0 ? 0 : (kc > GRID_N-1 ? GRID_N-1 : kc);
    int kr = (int)(py * 0.125f); kr = kr < 0 ? 0 : (kr > GRID_N-1 ? GRID_N-1 : kr);
    c_lo = kc - WHALF; c_lo = c_lo < 0 ? 0 : (c_lo > GRID_N-WIN ? GRID_N-WIN : c_lo);
    r_lo = kr - WHALF; r_lo = r_lo < 0 ? 0 : (r_lo > GRID_N-WIN ? GRID_N-WIN : r_lo);
}

// ---- setup 1: count points covering each cell ----
__global__ __launch_bounds__(1024) void ot_count_kernel(
    const float* __restrict__ pts, unsigned* __restrict__ ws_u32)
{
    const int img = blockIdx.x, p = threadIdx.x;
    unsigned* counts = ws_u32 + WS_COUNTS_B/4 + img*NCELL;
    float px = pts[(img*NPTS + p)*2 + 0];
    float py = pts[(img*NPTS + p)*2 + 1];
    int r_lo, c_lo; window_of(px, py, r_lo, c_lo);
#pragma unroll
    for (int wy = 0; wy < WIN; ++wy)
#pragma unroll
        for (int wx = 0; wx < WIN; ++wx)
            atomicAdd(&counts[(r_lo+wy)*GRID_N + c_lo + wx], 1u);
}

// ---- setup 2: exclusive prefix-sum of counts -> offs ----
__global__ __launch_bounds__(1024) void ot_scan_kernel(unsigned* __restrict__ ws_u32)
{
    const int img = blockIdx.x, t = threadIdx.x;
    const unsigned* counts = ws_u32 + WS_COUNTS_B/4 + img*NCELL;
    unsigned* offs = ws_u32 + WS_OFFS_B/4 + img*OFF_STRIDE;

    unsigned c[16];
    const uint4* c4 = (const uint4*)(counts + t*16);
#pragma unroll
    for (int j = 0; j < 4; ++j) {
        uint4 v = c4[j];
        c[j*4+0]=v.x; c[j*4+1]=v.y; c[j*4+2]=v.z; c[j*4+3]=v.w;
    }
    unsigned s = 0;
#pragma unroll
    for (int k = 0; k < 16; ++k) s += c[k];

    __shared__ unsigned sc[1024];
    sc[t] = s; __syncthreads();
    for (int d = 1; d < 1024; d <<= 1) {
        unsigned x = (t >= d) ? sc[t-d] : 0u;
        __syncthreads();
        sc[t] += x;
        __syncthreads();
    }
    unsigned run = sc[t] - s;
#pragma unroll
    for (int k = 0; k < 16; ++k) { offs[t*16+k] = run; run += c[k]; }
    if (t == 1023) offs[NCELL] = run;   // = 50176
}

// ---- setup 3: fill cell-major entries {K22 | pid10}; drains counts ----
__global__ __launch_bounds__(1024) void ot_fill_kernel(
    const float* __restrict__ pts, unsigned* __restrict__ ws_u32)
{
    const int img = blockIdx.x, p = threadIdx.x;
    unsigned* counts = ws_u32 + WS_COUNTS_B/4 + img*NCELL;
    const unsigned* offs = ws_u32 + WS_OFFS_B/4 + img*OFF_STRIDE;
    unsigned* entC = ws_u32 + WS_ENTC_B/4 + img*EPI;

    float px = pts[(img*NPTS + p)*2 + 0];
    float py = pts[(img*NPTS + p)*2 + 1];
    int r_lo, c_lo; window_of(px, py, r_lo, c_lo);
#pragma unroll
    for (int wy = 0; wy < WIN; ++wy) {
        float dy = py - (float)(8*(r_lo+wy) + 4);
#pragma unroll
        for (int wx = 0; wx < WIN; ++wx) {
            float dx = px - (float)(8*(c_lo+wx) + 4);
            float K = exp2f(C2 * (dx*dx + dy*dy));
            unsigned Kb = __float_as_uint(K);
            unsigned e = ((Kb + 0x200u) & 0xFFFFFC00u) | (unsigned)p;
            int cell = (r_lo+wy)*GRID_N + c_lo + wx;
            unsigned old = atomicSub(&counts[cell], 1u);
            entC[offs[cell] + old - 1u] = e;
        }
    }
}

// ---- setup 4: counting-sort points by band (kr>>3); init u = 1/N ----
__global__ __launch_bounds__(1024) void ot_psort_kernel(
    const float* __restrict__ pts, unsigned* __restrict__ ws_u32)
{
    const int img = blockIdx.x, t = threadIdx.x;
    __shared__ unsigned cnt[16];
    __shared__ unsigned pos[17];
    if (t < 16) cnt[t] = 0;
    __syncthreads();
    float py = pts[(img*NPTS + t)*2 + 1];
    int kr = (int)(py * 0.125f); kr = kr < 0 ? 0 : (kr > 127 ? 127 : kr);
    int b = kr >> 3;
    atomicAdd(&cnt[b], 1u);
    __syncthreads();
    if (t == 0) {
        unsigned run = 0;
        for (int i = 0; i < 16; ++i) { pos[i] = run; run += cnt[i]; }
        pos[16] = run;
    }
    __syncthreads();
    unsigned* bofs = ws_u32 + WS_BOFS_B/4 + img*32;
    if (t < 17) bofs[t] = pos[t];
    __syncthreads();
    unsigned slot = atomicAdd(&pos[b], 1u);
    ws_u32[WS_PLIST_B/4 + img*NPTS + slot] = (unsigned)t;
    ((float*)ws_u32)[WS_U_B/4 + img*NPTS + t] = 1.0f / (float)NPTS;
}

// ---- neighbor flag wait: lanes 0/1 poll bnd-1 / bnd+1 ----
__device__ __forceinline__ void wait_nbrs(unsigned* fl, int bnd, unsigned target)
{
    int lane = threadIdx.x;            // called with t < 64
    int nb = (lane == 0) ? bnd - 1 : (lane == 1 ? bnd + 1 : bnd);
    nb = (nb < 0 || nb > 15) ? bnd : nb;
    unsigned* p = fl + nb*16;
    int spins = 0;
    while (__hip_atomic_load(p, __ATOMIC_ACQUIRE, AGENT) < target) {
        __builtin_amdgcn_s_sleep(1);
        if (++spins > (1<<21)) break;  // safety: never triggers if logic sound
    }
}

// ---- main: 64 WGs (4 img x 16 bands); local 14-row v, u-only sharing ----
__global__ __launch_bounds__(TPB) void ot_main_kernel(
    const float* __restrict__ dens, const float* __restrict__ pts,
    unsigned* __restrict__ ws_u32)
{
    const int img = (int)blockIdx.x >> 4, bnd = (int)blockIdx.x & 15;
    const int t = threadIdx.x;
    float* ws_f = (float*)ws_u32;

    float*    loss  = ws_f;
    unsigned* fB    = ws_u32 + WS_FLAGS_B/4 + img*256;
    float*    u_g   = ws_f + WS_U_B/4 + img*NPTS;
    const unsigned* bofs  = ws_u32 + WS_BOFS_B/4 + img*32;
    const unsigned* plist = ws_u32 + WS_PLIST_B/4 + img*NPTS;
    const unsigned* offs  = ws_u32 + WS_OFFS_B/4 + img*OFF_STRIDE;
    const unsigned* entC  = ws_u32 + WS_ENTC_B/4 + img*EPI;

    __shared__ float u_lds[NPTS];
    __shared__ float v_loc[HCELLS];    // rows (8*bnd-3) .. (8*bnd+10)
    __shared__ float red[8];

    const int rowbase = bnd*8 - 3;

    // ---- static cell side: up to 4 halo cells/thread (stride TPB) ----
    unsigned co[4]; int ccnt[4]; float cb[4]; int cvi[4];
#pragma unroll
    for (int k = 0; k < 4; ++k) {
        int hc = t + k*TPB;            // 0..2047; valid < 1792
        ccnt[k] = 0; cvi[k] = 0; cb[k] = 0.f; co[k] = 0;
        if (hc < HCELLS) {
            int grow = rowbase + (hc >> 7);
            if (grow >= 0 && grow < GRID_N) {
                int gc = grow*GRID_N + (hc & 127);
                unsigned oA = offs[gc], oB = offs[gc+1];
                co[k] = oA; ccnt[k] = (int)(oB - oA);
                cb[k] = dens[img*NCELL + gc];
                cvi[k] = hc;
            }
        }
    }

    // ---- static point side: 4 threads/point ----
    const int p0 = (int)bofs[bnd], p1 = (int)bofs[bnd+1];
    const int npts = p1 - p0;
    const int sub = t & 3;
    const int idx = t >> 2;
    int mypid = -1, km = 0;
    float Kq[13], Kd2[13];
    int   cq[13];
    if (idx < npts && idx < 128) {
        mypid = (int)plist[p0 + idx];
        float px = pts[(img*NPTS + mypid)*2 + 0];
        float py = pts[(img*NPTS + mypid)*2 + 1];
        int r_lo, c_lo; window_of(px, py, r_lo, c_lo);
        int k = 0;
#pragma unroll
        for (int q = 0; q < 49; ++q) {
            if ((q & 3) == sub) {
                int wy = q / 7, wx = q % 7;
                float dx = px - (float)(8*(c_lo+wx) + 4);
                float dy = py - (float)(8*(r_lo+wy) + 4);
                float d2 = dx*dx + dy*dy;
                float K = exp2f(C2 * d2);
                Kq[k] = K; Kd2[k] = K * d2;
                cq[k] = (r_lo + wy - rowbase)*GRID_N + (c_lo + wx);
                ++k;
            }
        }
        km = k;   // 13 or 12
    }
    const int lo = (int)bofs[bnd > 0 ? bnd-1 : 0];
    const int hi = (int)bofs[bnd < 15 ? bnd+2 : 16];
    const float A = 1.0f / (float)NPTS;

    // init u_lds (all points start at A)
    u_lds[t] = A; u_lds[t + TPB] = A;

    float li_acc = 0.f;

    for (int it = 0; it < NITER; ++it) {
        if (it > 0) {
            if (t < 64) wait_nbrs(fB, bnd, (unsigned)it);
            __syncthreads();
            // stage neighbor-band u (own band's u_lds kept locally)
            for (int i = lo + t; i < p0; i += TPB) {
                unsigned pid = plist[i];
                u_lds[pid] = __hip_atomic_load(u_g + pid, __ATOMIC_RELAXED, AGENT);
            }
            for (int i = p1 + t; i < hi; i += TPB) {
                unsigned pid = plist[i];
                u_lds[pid] = __hip_atomic_load(u_g + pid, __ATOMIC_RELAXED, AGENT);
            }
        }
        __syncthreads();

        // ---- phase A (redundant halo): v_loc = b / (K^T u + eps) ----
#pragma unroll
        for (int k = 0; k < 4; ++k) {
            int cn = ccnt[k];
            if (cn > 0) {
                float s = 0.f;
                unsigned o = co[k];
                for (int e = 0; e < cn; ++e) {
                    unsigned E = entC[o + e];
                    s = fmaf(__uint_as_float(E & 0xFFFFFC00u), u_lds[E & 0x3FFu], s);
                }
                v_loc[cvi[k]] = cb[k] / (s + EPSF);
            }
        }
        __syncthreads();

        // ---- phase B: u = A / (K v + eps) for own points (local v!) ----
        if (mypid >= 0) {
            float kv = 0.f, kd = 0.f;
#pragma unroll
            for (int k = 0; k < 13; ++k) {
                if (k < km) {
                    float vj = v_loc[cq[k]];
                    kv = fmaf(Kq[k],  vj, kv);
                    kd = fmaf(Kd2[k], vj, kd);
                }
            }
            kv += __shfl_xor(kv, 1); kv += __shfl_xor(kv, 2);
            float u_new = A / (kv + EPSF);
            if (sub == 0) {
                u_lds[mypid] = u_new;
                __hip_atomic_store(u_g + mypid, u_new, __ATOMIC_RELAXED, AGENT);
            }
            if (it == NITER-1) {
                kd += __shfl_xor(kd, 1); kd += __shfl_xor(kd, 2);
                if (sub == 0) li_acc += u_new * kd;
            }
        }
        // rare overflow (band with >128 points): compute K inline
        for (int base2 = 128; base2 < npts; base2 += 128) {
            int idx2 = base2 + idx;
            if (idx2 < npts) {
                int pid2 = (int)plist[p0 + idx2];
                float px = pts[(img*NPTS + pid2)*2 + 0];
                float py = pts[(img*NPTS + pid2)*2 + 1];
                int r_lo, c_lo; window_of(px, py, r_lo, c_lo);
                float kv = 0.f, kd = 0.f;
                for (int q = sub; q < 49; q += 4) {
                    int wy = q / 7, wx = q % 7;
                    float dx = px - (float)(8*(c_lo+wx) + 4);
                    float dy = py - (float)(8*(r_lo+wy) + 4);
                    float d2 = dx*dx + dy*dy;
                    float K = exp2f(C2 * d2);
                    float vj = v_loc[(r_lo + wy - rowbase)*GRID_N + c_lo + wx];
                    kv = fmaf(K, vj, kv); kd = fmaf(K*d2, vj, kd);
                }
                kv += __shfl_xor(kv, 1); kv += __shfl_xor(kv, 2);
                float u_new = A / (kv + EPSF);
                if (sub == 0) {
                    u_lds[pid2] = u_new;
                    __hip_atomic_store(u_g + pid2, u_new, __ATOMIC_RELAXED, AGENT);
                }
                if (it == NITER-1) {
                    kd += __shfl_xor(kd, 1); kd += __shfl_xor(kd, 2);
                    if (sub == 0) li_acc += u_new * kd;
                }
            }
        }
        __syncthreads();
        if (t == 0)
            __hip_atomic_store(fB + bnd*16, (unsigned)(it+1), __ATOMIC_RELEASE, AGENT);
    }

    // ---- loss reduction ----
#pragma unroll
    for (int o = 32; o > 0; o >>= 1) li_acc += __shfl_down(li_acc, o);
    if ((t & 63) == 0) red[t >> 6] = li_acc;
    __syncthreads();
    if (t == 0) {
        float s = 0.f;
#pragma unroll
        for (int w = 0; w < 8; ++w) s += red[w];
        atomicAdd(&loss[img], s);
    }
}

__global__ void ot_finalize_kernel(const float* __restrict__ ws_f, float* __restrict__ out)
{
    float s = ws_f[0] + ws_f[1] + ws_f[2] + ws_f[3];
    out[0] = s;
    out[1] = s;
    out[2] = 0.f;
}

// ---- fallback (ws too small): R1-verified single-kernel path ----
__global__ __launch_bounds__(1024) void ot_fallback_kernel(
    const float* __restrict__ dens, const float* __restrict__ pts,
    float* __restrict__ out)
{
    const int img = blockIdx.x, t = threadIdx.x;
    __shared__ float sv[NCELL];
    __shared__ float redf[16];

    const float px = pts[(size_t)img*NPTS*2 + t*2 + 0];
    const float py = pts[(size_t)img*NPTS*2 + t*2 + 1];
    int r_lo, c_lo; window_of(px, py, r_lo, c_lo);

    float dx2[WIN], dy2[WIN];
#pragma unroll
    for (int j = 0; j < WIN; ++j) {
        float dx = px - (float)(8*(c_lo+j) + 4);
        float dy = py - (float)(8*(r_lo+j) + 4);
        dx2[j] = dx*dx; dy2[j] = dy*dy;
    }
    float K[WIN*WIN];
#pragma unroll
    for (int wy = 0; wy < WIN; ++wy)
#pragma unroll
        for (int wx = 0; wx < WIN; ++wx)
            K[wy*WIN+wx] = exp2f(C2 * (dx2[wx] + dy2[wy]));

    const int lbase = r_lo*GRID_N + c_lo;
    float breg[16];
    const float4* d4 = (const float4*)(dens + (size_t)img*NCELL + t*16);
#pragma unroll
    for (int j = 0; j < 4; ++j) {
        float4 v = d4[j];
        breg[j*4+0]=v.x; breg[j*4+1]=v.y; breg[j*4+2]=v.z; breg[j*4+3]=v.w;
    }
    const float A = 1.0f/(float)NPTS;
    float u = A;
    float4* sv4 = (float4*)sv;
    for (int it = 0; it < NITER; ++it) {
        __syncthreads();
#pragma unroll
        for (int j = 0; j < 4; ++j) sv4[t*4+j] = make_float4(0.f,0.f,0.f,0.f);
        __syncthreads();
#pragma unroll
        for (int wy = 0; wy < WIN; ++wy)
#pragma unroll
            for (int wx = 0; wx < WIN; ++wx)
                atomicAdd(&sv[lbase + wy*GRID_N + wx], u * K[wy*WIN+wx]);
        __syncthreads();
#pragma unroll
        for (int j = 0; j < 16; ++j) { int c = t*16+j; sv[c] = breg[j] / (sv[c] + EPSF); }
        __syncthreads();
        float kv = 0.f;
#pragma unroll
        for (int wy = 0; wy < WIN; ++wy)
#pragma unroll
            for (int wx = 0; wx < WIN; ++wx)
                kv = fmaf(K[wy*WIN+wx], sv[lbase + wy*GRID_N + wx], kv);
        u = A / (kv + EPSF);
    }
    float li = 0.f;
#pragma unroll
    for (int wy = 0; wy < WIN; ++wy)
#pragma unroll
        for (int wx = 0; wx < WIN; ++wx)
            li = fmaf(K[wy*WIN+wx] * (dx2[wx]+dy2[wy]), sv[lbase + wy*GRID_N + wx], li);
    li *= u;
#pragma unroll
    for (int o = 32; o > 0; o >>= 1) li += __shfl_down(li, o);
    if ((t & 63) == 0) redf[t >> 6] = li;
    __syncthreads();
    if (t == 0) {
        float s = 0.f;
#pragma unroll
        for (int w = 0; w < 16; ++w) s += redf[w];
        atomicAdd(&out[0], s);
        atomicAdd(&out[1], s);
    }
}

extern "C" void kernel_launch(void* const* d_in, const int* in_sizes, int n_in,
                              void* d_out, int out_size, void* d_ws, size_t ws_size,
                              hipStream_t stream)
{
    const float* dens = (const float*)d_in[0];   // [4,1,128,128]
    const float* pts  = (const float*)d_in[2];   // [4,1024,2]
    float* out = (float*)d_out;
    unsigned* ws_u32 = (unsigned*)d_ws;

    if (ws_size < (size_t)WS_TOTAL) {   // insurance: slow-but-correct path
        hipMemsetAsync(d_out, 0, 3*sizeof(float), stream);
        ot_fallback_kernel<<<NIMG, 1024, 0, stream>>>(dens, pts, out);
        return;
    }

    hipMemsetAsync(d_ws, 0, ZERO_BYTES, stream);   // loss+flags+u+counts
    ot_count_kernel   <<<NIMG, 1024, 0, stream>>>(pts, ws_u32);
    ot_scan_kernel    <<<NIMG, 1024, 0, stream>>>(ws_u32);
    ot_fill_kernel    <<<NIMG, 1024, 0, stream>>>(pts, ws_u32);
    ot_psort_kernel   <<<NIMG, 1024, 0, stream>>>(pts, ws_u32);
    ot_main_kernel    <<<NIMG*NBAND, TPB, 0, stream>>>(dens, pts, ws_u32);
    ot_finalize_kernel<<<1, 1, 0, stream>>>((const float*)d_ws, out);
}